// Round 11
// baseline (535.392 us; speedup 1.0000x reference)
//
#include <hip/hip_runtime.h>
#include <hip/hip_bf16.h>

#define N_NODES 50000
#define N_EDGES 800000
#define NPATH 3
#define NBKT 196                    // ceil(50000/256) buckets per path
#define NBKT3 (NPATH * NBKT)        // 588
#define NCHUNKBLK 256               // blocks for count/scatter passes
#define CHUNK 9375                  // (3*800000)/256 exact
#define LDS_STRIDE 260              // 256 + 4 pad

typedef __attribute__((ext_vector_type(8))) short short8;
typedef __attribute__((ext_vector_type(4))) float v4f;

// RNE f32 -> bf16 bits, also returns the rounded-back float.
__device__ __forceinline__ short f2bf(float v, float* back) {
  unsigned u = __float_as_uint(v);
  unsigned r = (u + 0x7FFFu + ((u >> 16) & 1u)) >> 16;
  *back = __uint_as_float(r << 16);
  return (short)r;
}

// ---------------------------------------------------------------------------
// CSR build passes A-E (unchanged from R7; zero global atomics).
// ---------------------------------------------------------------------------
__global__ __launch_bounds__(256) void blk_count_kernel(
    const int* __restrict__ ei, int* __restrict__ cntmat) {
  __shared__ int lcnt[NBKT3];
  const int t = threadIdx.x, blk = blockIdx.x;
  for (int j = t; j < NBKT3; j += 256) lcnt[j] = 0;
  __syncthreads();
  const int lo = blk * CHUNK, hi = lo + CHUNK;
  for (int idx = lo + t; idx < hi; idx += 256) {
    int p = idx / N_EDGES, e = idx - p * N_EDGES;
    int d = ei[p * 2 * N_EDGES + N_EDGES + e];
    atomicAdd(&lcnt[p * NBKT + (d >> 8)], 1);   // LDS atomic
  }
  __syncthreads();
  for (int j = t; j < NBKT3; j += 256) cntmat[blk * NBKT3 + j] = lcnt[j];
}

__global__ __launch_bounds__(256) void col_scan_kernel(
    const int* __restrict__ cntmat, int* __restrict__ pos, int* __restrict__ btot) {
  __shared__ int tmp[256];
  const int b = blockIdx.x, t = threadIdx.x;
  int v = cntmat[t * NBKT3 + b];
  tmp[t] = v;
  __syncthreads();
  for (int ofs = 1; ofs < 256; ofs <<= 1) {
    int x = (t >= ofs) ? tmp[t - ofs] : 0;
    __syncthreads();
    tmp[t] += x;
    __syncthreads();
  }
  pos[b * 256 + t] = tmp[t] - v;
  if (t == 255) btot[b] = tmp[255];
}

__global__ __launch_bounds__(1024) void bucket_scan_kernel(
    const int* __restrict__ btot, int* __restrict__ boff) {
  __shared__ int tmp[1024];
  const int t = threadIdx.x;
  int v = (t < NBKT3) ? btot[t] : 0;
  tmp[t] = v;
  __syncthreads();
  for (int ofs = 1; ofs < 1024; ofs <<= 1) {
    int x = (t >= ofs) ? tmp[t - ofs] : 0;
    __syncthreads();
    tmp[t] += x;
    __syncthreads();
  }
  if (t < NBKT3) boff[t] = tmp[t] - v;
}

__global__ __launch_bounds__(256) void scatter_det_kernel(
    const int* __restrict__ ei, const int* __restrict__ boff,
    const int* __restrict__ pos, int2* __restrict__ ebuf) {
  __shared__ int cursor[NBKT3];
  const int t = threadIdx.x, blk = blockIdx.x;
  for (int j = t; j < NBKT3; j += 256)
    cursor[j] = boff[j] + pos[j * 256 + blk];
  __syncthreads();
  const int lo = blk * CHUNK, hi = lo + CHUNK;
  for (int idx = lo + t; idx < hi; idx += 256) {
    int p = idx / N_EDGES, e = idx - p * N_EDGES;
    int s = ei[p * 2 * N_EDGES + e];
    int d = ei[p * 2 * N_EDGES + N_EDGES + e];
    int ps = atomicAdd(&cursor[p * NBKT + (d >> 8)], 1);   // LDS atomic
    ebuf[ps] = make_int2(s, d);
  }
}

__global__ __launch_bounds__(256) void bucket_csr_kernel(
    const int2* __restrict__ ebuf, const int* __restrict__ boff,
    const int* __restrict__ btot,
    int* __restrict__ off3, int* __restrict__ deg3, int* __restrict__ csr_src) {
  __shared__ int cnt[256], excl[256], cur[256];
  const int b = blockIdx.x;
  const int t = threadIdx.x;
  const int p = b / NBKT;
  const int node_base = (b - p * NBKT) * 256;
  const int start = boff[b];
  const int ecount = btot[b];

  cnt[t] = 0;
  __syncthreads();
  for (int i = t; i < ecount; i += 256)
    atomicAdd(&cnt[ebuf[start + i].y & 255], 1);
  __syncthreads();

  int v = cnt[t];
  excl[t] = v;
  __syncthreads();
  for (int ofs = 1; ofs < 256; ofs <<= 1) {
    int x = (t >= ofs) ? excl[t - ofs] : 0;
    __syncthreads();
    excl[t] += x;
    __syncthreads();
  }
  int my_excl = excl[t] - v;
  cur[t] = my_excl;
  const int node = node_base + t;
  if (node < N_NODES) {
    off3[p * N_NODES + node] = start + my_excl;   // GLOBAL offset
    deg3[p * N_NODES + node] = v;
  }
  __syncthreads();

  for (int i = t; i < ecount; i += 256) {
    int2 e = ebuf[start + i];
    int pos2 = atomicAdd(&cur[e.y & 255], 1);
    csr_src[start + pos2] = e.x;
  }
}

// ---------------------------------------------------------------------------
// Fused prep (all paths, one dispatch).
// ---------------------------------------------------------------------------
__global__ __launch_bounds__(256) void prep_kernel(
    const float* __restrict__ fc_w, const float* __restrict__ attn_l,
    const float* __restrict__ attn_r, const float* __restrict__ sem_w,
    __hip_bfloat16* __restrict__ Wf_hi, __hip_bfloat16* __restrict__ Wf_lo,
    __hip_bfloat16* __restrict__ Bs_hi, __hip_bfloat16* __restrict__ Bs_lo) {
  const int p = blockIdx.x / 33;
  const int unit = blockIdx.x % 33;
  const int t = threadIdx.x;
  if (unit < 17) {
    const float* W = fc_w + (size_t)p * 128 * 256;
    int idx = unit * 256 + t;        // < 4352 = 4*17*64
    int lane = idx & 63;
    int tmp = idx >> 6;              // kc*17 + nt
    int nt = tmp % 17, kc = tmp / 17;
    int l15 = lane & 15, quad = lane >> 4;
    __hip_bfloat16* oh = Wf_hi + (size_t)p * 34816;
    __hip_bfloat16* ol = Wf_lo + (size_t)p * 34816;
    for (int j = 0; j < 8; j++) {
      int k = kc * 32 + quad * 8 + j;
      float v;
      if (nt < 16) {
        v = W[k * 256 + nt * 16 + l15];
      } else {
        int h8 = l15 & 7;
        const float* av = ((l15 < 8) ? attn_l : attn_r) + (size_t)p * 256 + h8 * 32;
        v = 0.f;
        for (int dd = 0; dd < 32; dd++)
          v = fmaf(W[k * 256 + h8 * 32 + dd], av[dd], v);
      }
      float back, back2;
      short hb = f2bf(v, &back);
      short lb = f2bf(v - back, &back2);
      ((short*)oh)[(tmp * 64 + lane) * 8 + j] = hb;
      ((short*)ol)[(tmp * 64 + lane) * 8 + j] = lb;
    }
  } else {
    const float* Ws = sem_w + (size_t)p * 256 * 128;
    int idx = (unit - 17) * 256 + t; // < 4096 = 8*8*64
    int lane = idx & 63;
    int tmp = idx >> 6;              // kc*8 + nt
    int nt = tmp & 7, kc = tmp >> 3;
    int l15 = lane & 15, quad = lane >> 4;
    __hip_bfloat16* oh = Bs_hi + (size_t)p * 32768;
    __hip_bfloat16* ol = Bs_lo + (size_t)p * 32768;
    for (int j = 0; j < 8; j++) {
      int k = kc * 32 + quad * 8 + j;
      float v = Ws[k * 128 + nt * 16 + l15];
      float back, back2;
      short hb = f2bf(v, &back);
      short lb = f2bf(v - back, &back2);
      ((short*)oh)[(tmp * 64 + lane) * 8 + j] = hb;
      ((short*)ol)[(tmp * 64 + lane) * 8 + j] = lb;
    }
  }
}

// ---------------------------------------------------------------------------
// MFMA 1 v2: 2 M-tiles (32 rows) per wave — B fragments loaded ONCE per
// (kc,nt) and shared by both tiles, halving L2 weight traffic.
// grid = (1563, NPATH); last block has only tile 0 (50000 = 32*1562 + 16).
// ---------------------------------------------------------------------------
__global__ __launch_bounds__(64) void feat_mfma_kernel(
    const float* __restrict__ h,
    const __hip_bfloat16* __restrict__ Wf_hi_all,
    const __hip_bfloat16* __restrict__ Wf_lo_all,
    __hip_bfloat16* __restrict__ feat3, float* __restrict__ el3,
    float* __restrict__ er3) {
  const int p = blockIdx.y;
  const __hip_bfloat16* Wf_hi = Wf_hi_all + (size_t)p * 34816;
  const __hip_bfloat16* Wf_lo = Wf_lo_all + (size_t)p * 34816;
  __hip_bfloat16* feat = feat3 + (size_t)p * N_NODES * 256;
  float* el = el3 + (size_t)p * N_NODES * 8;
  float* er = er3 + (size_t)p * N_NODES * 8;

  const int lane = threadIdx.x;
  const int l15 = lane & 15, quad = lane >> 4;
  const int m0 = blockIdx.x * 32;
  const bool okB = (m0 + 16) < N_NODES;   // tile-1 validity (only last block fails)
  const int mrowA = m0 + l15;
  const int mrowB = okB ? (m0 + 16 + l15) : mrowA;

  v4f acc0[17], acc1[17];
#pragma unroll
  for (int nt = 0; nt < 17; nt++) {
    acc0[nt] = {0.f, 0.f, 0.f, 0.f};
    acc1[nt] = {0.f, 0.f, 0.f, 0.f};
  }

#pragma unroll
  for (int kc = 0; kc < 4; kc++) {
    const float* hrowA = h + (size_t)mrowA * 128 + kc * 32 + quad * 8;
    const float* hrowB = h + (size_t)mrowB * 128 + kc * 32 + quad * 8;
    float4 a0 = *(const float4*)hrowA;
    float4 a1 = *(const float4*)(hrowA + 4);
    float4 b0 = *(const float4*)hrowB;
    float4 b1 = *(const float4*)(hrowB + 4);
    float fvA[8] = {a0.x, a0.y, a0.z, a0.w, a1.x, a1.y, a1.z, a1.w};
    float fvB[8] = {b0.x, b0.y, b0.z, b0.w, b1.x, b1.y, b1.z, b1.w};
    short8 ahiA, aloA, ahiB, aloB;
#pragma unroll
    for (int q = 0; q < 8; q++) {
      float back, back2;
      ahiA[q] = f2bf(fvA[q], &back);
      aloA[q] = f2bf(fvA[q] - back, &back2);
      ahiB[q] = f2bf(fvB[q], &back);
      aloB[q] = f2bf(fvB[q] - back, &back2);
    }
#pragma unroll
    for (int nt = 0; nt < 17; nt++) {
      const int o = ((kc * 17 + nt) * 64 + lane) * 8;
      short8 bhi = *(const short8*)(Wf_hi + o);
      short8 blo = *(const short8*)(Wf_lo + o);
      acc0[nt] = __builtin_amdgcn_mfma_f32_16x16x32_bf16(ahiA, bhi, acc0[nt], 0, 0, 0);
      acc0[nt] = __builtin_amdgcn_mfma_f32_16x16x32_bf16(ahiA, blo, acc0[nt], 0, 0, 0);
      acc0[nt] = __builtin_amdgcn_mfma_f32_16x16x32_bf16(aloA, bhi, acc0[nt], 0, 0, 0);
      acc1[nt] = __builtin_amdgcn_mfma_f32_16x16x32_bf16(ahiB, bhi, acc1[nt], 0, 0, 0);
      acc1[nt] = __builtin_amdgcn_mfma_f32_16x16x32_bf16(ahiB, blo, acc1[nt], 0, 0, 0);
      acc1[nt] = __builtin_amdgcn_mfma_f32_16x16x32_bf16(aloB, bhi, acc1[nt], 0, 0, 0);
    }
  }

#pragma unroll
  for (int nt = 0; nt < 16; nt++)
#pragma unroll
    for (int r = 0; r < 4; r++) {
      int m = m0 + quad * 4 + r;
      feat[(size_t)m * 256 + nt * 16 + l15] = __float2bfloat16(acc0[nt][r]);
      if (okB)
        feat[(size_t)(m + 16) * 256 + nt * 16 + l15] = __float2bfloat16(acc1[nt][r]);
    }
#pragma unroll
  for (int r = 0; r < 4; r++) {
    int m = m0 + quad * 4 + r;
    float v0 = acc0[16][r];
    if (l15 < 8) el[m * 8 + l15] = v0;
    else         er[m * 8 + (l15 - 8)] = v0;
    if (okB) {
      float v1 = acc1[16][r];
      if (l15 < 8) el[(m + 16) * 8 + l15] = v1;
      else         er[(m + 16) * 8 + (l15 - 8)] = v1;
    }
  }
}

// ---------------------------------------------------------------------------
// Edge helpers for agg_sem (aggregate 4 / 1 edges into per-lane accumulators).
// ---------------------------------------------------------------------------
__device__ __forceinline__ void edge4(
    const int* __restrict__ lst, int j, const float* __restrict__ el,
    float erh, const ushort* __restrict__ fp, int lane, int hh,
    float& aD, float& aN0, float& aN1, float& aN2, float& aN3) {
  int s0 = lst[j], s1 = lst[j + 1], s2 = lst[j + 2], s3 = lst[j + 3];
  float x0 = el[s0 * 8 + hh] + erh;
  float x1 = el[s1 * 8 + hh] + erh;
  float x2 = el[s2 * 8 + hh] + erh;
  float x3 = el[s3 * 8 + hh] + erh;
  ushort4 f0 = *(const ushort4*)(fp + (size_t)s0 * 256 + lane * 4);
  ushort4 f1 = *(const ushort4*)(fp + (size_t)s1 * 256 + lane * 4);
  ushort4 f2 = *(const ushort4*)(fp + (size_t)s2 * 256 + lane * 4);
  ushort4 f3 = *(const ushort4*)(fp + (size_t)s3 * 256 + lane * 4);
  x0 = x0 > 0.f ? x0 : 0.2f * x0;  float e0 = __expf(x0);
  x1 = x1 > 0.f ? x1 : 0.2f * x1;  float e1 = __expf(x1);
  x2 = x2 > 0.f ? x2 : 0.2f * x2;  float e2 = __expf(x2);
  x3 = x3 > 0.f ? x3 : 0.2f * x3;  float e3 = __expf(x3);
  aD += e0 + e1 + e2 + e3;
  aN0 = fmaf(e0, __uint_as_float((unsigned)f0.x << 16), aN0);
  aN1 = fmaf(e0, __uint_as_float((unsigned)f0.y << 16), aN1);
  aN2 = fmaf(e0, __uint_as_float((unsigned)f0.z << 16), aN2);
  aN3 = fmaf(e0, __uint_as_float((unsigned)f0.w << 16), aN3);
  aN0 = fmaf(e1, __uint_as_float((unsigned)f1.x << 16), aN0);
  aN1 = fmaf(e1, __uint_as_float((unsigned)f1.y << 16), aN1);
  aN2 = fmaf(e1, __uint_as_float((unsigned)f1.z << 16), aN2);
  aN3 = fmaf(e1, __uint_as_float((unsigned)f1.w << 16), aN3);
  aN0 = fmaf(e2, __uint_as_float((unsigned)f2.x << 16), aN0);
  aN1 = fmaf(e2, __uint_as_float((unsigned)f2.y << 16), aN1);
  aN2 = fmaf(e2, __uint_as_float((unsigned)f2.z << 16), aN2);
  aN3 = fmaf(e2, __uint_as_float((unsigned)f2.w << 16), aN3);
  aN0 = fmaf(e3, __uint_as_float((unsigned)f3.x << 16), aN0);
  aN1 = fmaf(e3, __uint_as_float((unsigned)f3.y << 16), aN1);
  aN2 = fmaf(e3, __uint_as_float((unsigned)f3.z << 16), aN2);
  aN3 = fmaf(e3, __uint_as_float((unsigned)f3.w << 16), aN3);
}

__device__ __forceinline__ void edge1(
    const int* __restrict__ lst, int j, const float* __restrict__ el,
    float erh, const ushort* __restrict__ fp, int lane, int hh,
    float& aD, float& aN0, float& aN1, float& aN2, float& aN3) {
  int s = lst[j];
  float x = el[s * 8 + hh] + erh;
  ushort4 f0 = *(const ushort4*)(fp + (size_t)s * 256 + lane * 4);
  x = x > 0.f ? x : 0.2f * x;
  float e0 = __expf(x);
  aD += e0;
  aN0 = fmaf(e0, __uint_as_float((unsigned)f0.x << 16), aN0);
  aN1 = fmaf(e0, __uint_as_float((unsigned)f0.y << 16), aN1);
  aN2 = fmaf(e0, __uint_as_float((unsigned)f0.z << 16), aN2);
  aN3 = fmaf(e0, __uint_as_float((unsigned)f0.w << 16), aN3);
}

// ---------------------------------------------------------------------------
// Fused aggregate + semantic GEMM. 512 threads (8 waves) per block; block
// handles 16 dst nodes. Edge phase: wave w aggregates nodes 2w, 2w+1 with
// the two edge streams INTERLEAVED (8 gathers in flight). MFMA phase: wave w
// computes N-tile w of rows(16x256) @ sem_w(256x128), accumulates into out.
// ---------------------------------------------------------------------------
__global__ __launch_bounds__(512) void agg_sem_kernel(
    const int* __restrict__ csr_src, const int* __restrict__ off,
    const int* __restrict__ deg,
    const float* __restrict__ el, const float* __restrict__ er,
    const __hip_bfloat16* __restrict__ feat,
    const __hip_bfloat16* __restrict__ Bs_hi, const __hip_bfloat16* __restrict__ Bs_lo,
    const float* __restrict__ bias, float* __restrict__ out, int mode) {
  __shared__ float Arow[16 * LDS_STRIDE];
  const int t = threadIdx.x;
  const int w = t >> 6, lane = t & 63;
  const int hh = lane >> 3;            // head of this lane's 4 channels
  const int node_base = blockIdx.x * 16;
  const ushort* fp = (const ushort*)feat;

  // ---- edge phase: nodes 2w and 2w+1, interleaved streams ----
  const int node0 = node_base + 2 * w;
  const int node1 = node0 + 1;
  const int n0 = deg[node0], n1 = deg[node1];
  const int* lst0 = csr_src + off[node0];
  const int* lst1 = csr_src + off[node1];
  const float erh0 = er[node0 * 8 + hh];
  const float erh1 = er[node1 * 8 + hh];

  float p0 = 0.f, p1 = 0.f, p2 = 0.f, p3 = 0.f, pD = 0.f;   // node0
  float q0 = 0.f, q1 = 0.f, q2 = 0.f, q3 = 0.f, qD = 0.f;   // node1

  const int nmin = min(n0, n1);
  int j = 0;
  for (; j + 4 <= nmin; j += 4) {
    edge4(lst0, j, el, erh0, fp, lane, hh, pD, p0, p1, p2, p3);
    edge4(lst1, j, el, erh1, fp, lane, hh, qD, q0, q1, q2, q3);
  }
  int ja = j;
  for (; ja + 4 <= n0; ja += 4) edge4(lst0, ja, el, erh0, fp, lane, hh, pD, p0, p1, p2, p3);
  for (; ja < n0; ja++)         edge1(lst0, ja, el, erh0, fp, lane, hh, pD, p0, p1, p2, p3);
  int jb = j;
  for (; jb + 4 <= n1; jb += 4) edge4(lst1, jb, el, erh1, fp, lane, hh, qD, q0, q1, q2, q3);
  for (; jb < n1; jb++)         edge1(lst1, jb, el, erh1, fp, lane, hh, qD, q0, q1, q2, q3);

  {
    float inv = (n0 > 0) ? 1.f / pD : 0.f;
    float r0 = p0 * inv, r1 = p1 * inv, r2 = p2 * inv, r3 = p3 * inv;
    r0 = r0 > 0.f ? r0 : (__expf(r0) - 1.f);
    r1 = r1 > 0.f ? r1 : (__expf(r1) - 1.f);
    r2 = r2 > 0.f ? r2 : (__expf(r2) - 1.f);
    r3 = r3 > 0.f ? r3 : (__expf(r3) - 1.f);
    *(float4*)&Arow[(2 * w) * LDS_STRIDE + lane * 4] = make_float4(r0, r1, r2, r3);
  }
  {
    float inv = (n1 > 0) ? 1.f / qD : 0.f;
    float r0 = q0 * inv, r1 = q1 * inv, r2 = q2 * inv, r3 = q3 * inv;
    r0 = r0 > 0.f ? r0 : (__expf(r0) - 1.f);
    r1 = r1 > 0.f ? r1 : (__expf(r1) - 1.f);
    r2 = r2 > 0.f ? r2 : (__expf(r2) - 1.f);
    r3 = r3 > 0.f ? r3 : (__expf(r3) - 1.f);
    *(float4*)&Arow[(2 * w + 1) * LDS_STRIDE + lane * 4] = make_float4(r0, r1, r2, r3);
  }
  __syncthreads();

  // ---- MFMA phase: wave w -> N-tile nt = w ----
  const int nt = w;
  const int l15 = lane & 15, quad = lane >> 4;
  v4f acc = {0.f, 0.f, 0.f, 0.f};
#pragma unroll
  for (int kc = 0; kc < 8; kc++) {
    const float* ap = &Arow[l15 * LDS_STRIDE + kc * 32 + quad * 8];
    float4 a0 = *(const float4*)ap;
    float4 a1 = *(const float4*)(ap + 4);
    float fv[8] = {a0.x, a0.y, a0.z, a0.w, a1.x, a1.y, a1.z, a1.w};
    short8 ahi, alo;
#pragma unroll
    for (int q = 0; q < 8; q++) {
      float back, back2;
      ahi[q] = f2bf(fv[q], &back);
      alo[q] = f2bf(fv[q] - back, &back2);
    }
    const int o = ((kc * 8 + nt) * 64 + lane) * 8;
    short8 bhi = *(const short8*)(Bs_hi + o);
    short8 blo = *(const short8*)(Bs_lo + o);
    acc = __builtin_amdgcn_mfma_f32_16x16x32_bf16(ahi, bhi, acc, 0, 0, 0);
    acc = __builtin_amdgcn_mfma_f32_16x16x32_bf16(ahi, blo, acc, 0, 0, 0);
    acc = __builtin_amdgcn_mfma_f32_16x16x32_bf16(alo, bhi, acc, 0, 0, 0);
  }

#pragma unroll
  for (int r = 0; r < 4; r++) {
    int m = node_base + quad * 4 + r;
    size_t o = (size_t)m * 128 + nt * 16 + l15;
    float v = acc[r];
    if (mode == 0) v += bias[nt * 16 + l15];
    else           v += out[o];
    out[o] = v;
  }
}

// ---------------------------------------------------------------------------
extern "C" void kernel_launch(void* const* d_in, const int* in_sizes, int n_in,
                              void* d_out, int out_size, void* d_ws, size_t ws_size,
                              hipStream_t stream) {
  const float* h      = (const float*)d_in[0];
  const int*   ei     = (const int*)d_in[1];
  const float* fc_w   = (const float*)d_in[2];
  const float* attn_l = (const float*)d_in[3];
  const float* attn_r = (const float*)d_in[4];
  const float* sem_w  = (const float*)d_in[5];
  const float* sem_b  = (const float*)d_in[6];
  float* out = (float*)d_out;

  // workspace layout (bytes) — total ~118.4 MB (<=132.8 MB proven safe)
  char* ws = (char*)d_ws;
  __hip_bfloat16* feat3 = (__hip_bfloat16*)ws;                     // 76.8 MB
  float* el3     = (float*)(ws + 76800000);                        // 4.8 MB
  float* er3     = (float*)(ws + 81600000);                        // 4.8 MB
  int*   csr_src = (int*)(ws + 86400000);                          // 9.6 MB
  int2*  ebuf    = (int2*)(ws + 96000000);                         // 19.2 MB
  int*   deg3    = (int*)(ws + 115200000);                         // 0.6 MB
  int*   off3    = (int*)(ws + 115800000);                         // 0.6 MB
  int*   cntmat  = (int*)(ws + 116400000);                         // 602 KB
  int*   posm    = (int*)(ws + 117050000);                         // 602 KB
  int*   btot    = (int*)(ws + 117700000);                         // 2.4 KB
  int*   boff    = (int*)(ws + 117710000);                         // 2.4 KB
  __hip_bfloat16* Wf_hi = (__hip_bfloat16*)(ws + 117800000);       // 3x69632 B
  __hip_bfloat16* Wf_lo = (__hip_bfloat16*)(ws + 118050000);       // 3x69632 B
  __hip_bfloat16* Bs_hi = (__hip_bfloat16*)(ws + 118300000);       // 3x65536 B
  __hip_bfloat16* Bs_lo = (__hip_bfloat16*)(ws + 118550000);       // 3x65536 B

  // --- CSR build (deterministic counting sort) + fused weight prep ---
  blk_count_kernel<<<NCHUNKBLK, 256, 0, stream>>>(ei, cntmat);
  col_scan_kernel<<<NBKT3, 256, 0, stream>>>(cntmat, posm, btot);
  bucket_scan_kernel<<<1, 1024, 0, stream>>>(btot, boff);
  scatter_det_kernel<<<NCHUNKBLK, 256, 0, stream>>>(ei, boff, posm, ebuf);
  bucket_csr_kernel<<<NBKT3, 256, 0, stream>>>(ebuf, boff, btot, off3, deg3, csr_src);
  prep_kernel<<<NPATH * 33, 256, 0, stream>>>(fc_w, attn_l, attn_r, sem_w,
                                              Wf_hi, Wf_lo, Bs_hi, Bs_lo);

  // --- all 3 feat GEMMs in one dispatch (2 M-tiles per wave) ---
  feat_mfma_kernel<<<dim3((N_NODES + 31) / 32, NPATH), 64, 0, stream>>>(
      h, Wf_hi, Wf_lo, feat3, el3, er3);

  // --- fused aggregate + semantic GEMM per path (out accumulates) ---
  for (int p = 0; p < NPATH; p++) {
    agg_sem_kernel<<<N_NODES / 16, 512, 0, stream>>>(
        csr_src, off3 + p * N_NODES, deg3 + p * N_NODES,
        el3 + (size_t)p * N_NODES * 8, er3 + (size_t)p * N_NODES * 8,
        feat3 + (size_t)p * N_NODES * 256,
        Bs_hi + (size_t)p * 32768, Bs_lo + (size_t)p * 32768,
        sem_b, out, p);
  }
}

// Round 12
// 490.079 us; speedup vs baseline: 1.0925x; 1.0925x over previous
//
#include <hip/hip_runtime.h>
#include <hip/hip_bf16.h>

#define N_NODES 50000
#define N_EDGES 800000
#define NPATH 3
#define NBKT 196                    // ceil(50000/256) buckets per path
#define NBKT3 (NPATH * NBKT)        // 588
#define NCHUNKBLK 256               // blocks for count/scatter passes
#define CHUNK 9375                  // (3*800000)/256 exact
#define LDS_STRIDE 260              // 256 + 4 pad

typedef __attribute__((ext_vector_type(8))) short short8;
typedef __attribute__((ext_vector_type(4))) float v4f;

// RNE f32 -> bf16 bits, also returns the rounded-back float.
__device__ __forceinline__ short f2bf(float v, float* back) {
  unsigned u = __float_as_uint(v);
  unsigned r = (u + 0x7FFFu + ((u >> 16) & 1u)) >> 16;
  *back = __uint_as_float(r << 16);
  return (short)r;
}

__device__ __forceinline__ float bfu(unsigned x) {
  return __uint_as_float(x << 16);
}

// ---------------------------------------------------------------------------
// CSR build passes A-E (unchanged from R7; zero global atomics).
// ---------------------------------------------------------------------------
__global__ __launch_bounds__(256) void blk_count_kernel(
    const int* __restrict__ ei, int* __restrict__ cntmat) {
  __shared__ int lcnt[NBKT3];
  const int t = threadIdx.x, blk = blockIdx.x;
  for (int j = t; j < NBKT3; j += 256) lcnt[j] = 0;
  __syncthreads();
  const int lo = blk * CHUNK, hi = lo + CHUNK;
  for (int idx = lo + t; idx < hi; idx += 256) {
    int p = idx / N_EDGES, e = idx - p * N_EDGES;
    int d = ei[p * 2 * N_EDGES + N_EDGES + e];
    atomicAdd(&lcnt[p * NBKT + (d >> 8)], 1);   // LDS atomic
  }
  __syncthreads();
  for (int j = t; j < NBKT3; j += 256) cntmat[blk * NBKT3 + j] = lcnt[j];
}

__global__ __launch_bounds__(256) void col_scan_kernel(
    const int* __restrict__ cntmat, int* __restrict__ pos, int* __restrict__ btot) {
  __shared__ int tmp[256];
  const int b = blockIdx.x, t = threadIdx.x;
  int v = cntmat[t * NBKT3 + b];
  tmp[t] = v;
  __syncthreads();
  for (int ofs = 1; ofs < 256; ofs <<= 1) {
    int x = (t >= ofs) ? tmp[t - ofs] : 0;
    __syncthreads();
    tmp[t] += x;
    __syncthreads();
  }
  pos[b * 256 + t] = tmp[t] - v;
  if (t == 255) btot[b] = tmp[255];
}

__global__ __launch_bounds__(1024) void bucket_scan_kernel(
    const int* __restrict__ btot, int* __restrict__ boff) {
  __shared__ int tmp[1024];
  const int t = threadIdx.x;
  int v = (t < NBKT3) ? btot[t] : 0;
  tmp[t] = v;
  __syncthreads();
  for (int ofs = 1; ofs < 1024; ofs <<= 1) {
    int x = (t >= ofs) ? tmp[t - ofs] : 0;
    __syncthreads();
    tmp[t] += x;
    __syncthreads();
  }
  if (t < NBKT3) boff[t] = tmp[t] - v;
}

__global__ __launch_bounds__(256) void scatter_det_kernel(
    const int* __restrict__ ei, const int* __restrict__ boff,
    const int* __restrict__ pos, int2* __restrict__ ebuf) {
  __shared__ int cursor[NBKT3];
  const int t = threadIdx.x, blk = blockIdx.x;
  for (int j = t; j < NBKT3; j += 256)
    cursor[j] = boff[j] + pos[j * 256 + blk];
  __syncthreads();
  const int lo = blk * CHUNK, hi = lo + CHUNK;
  for (int idx = lo + t; idx < hi; idx += 256) {
    int p = idx / N_EDGES, e = idx - p * N_EDGES;
    int s = ei[p * 2 * N_EDGES + e];
    int d = ei[p * 2 * N_EDGES + N_EDGES + e];
    int ps = atomicAdd(&cursor[p * NBKT + (d >> 8)], 1);   // LDS atomic
    ebuf[ps] = make_int2(s, d);
  }
}

__global__ __launch_bounds__(256) void bucket_csr_kernel(
    const int2* __restrict__ ebuf, const int* __restrict__ boff,
    const int* __restrict__ btot,
    int* __restrict__ off3, int* __restrict__ deg3, int* __restrict__ csr_src) {
  __shared__ int cnt[256], excl[256], cur[256];
  const int b = blockIdx.x;
  const int t = threadIdx.x;
  const int p = b / NBKT;
  const int node_base = (b - p * NBKT) * 256;
  const int start = boff[b];
  const int ecount = btot[b];

  cnt[t] = 0;
  __syncthreads();
  for (int i = t; i < ecount; i += 256)
    atomicAdd(&cnt[ebuf[start + i].y & 255], 1);
  __syncthreads();

  int v = cnt[t];
  excl[t] = v;
  __syncthreads();
  for (int ofs = 1; ofs < 256; ofs <<= 1) {
    int x = (t >= ofs) ? excl[t - ofs] : 0;
    __syncthreads();
    excl[t] += x;
    __syncthreads();
  }
  int my_excl = excl[t] - v;
  cur[t] = my_excl;
  const int node = node_base + t;
  if (node < N_NODES) {
    off3[p * N_NODES + node] = start + my_excl;   // GLOBAL offset
    deg3[p * N_NODES + node] = v;
  }
  __syncthreads();

  for (int i = t; i < ecount; i += 256) {
    int2 e = ebuf[start + i];
    int pos2 = atomicAdd(&cur[e.y & 255], 1);
    csr_src[start + pos2] = e.x;
  }
}

// ---------------------------------------------------------------------------
// Fused prep (all paths, one dispatch).
// ---------------------------------------------------------------------------
__global__ __launch_bounds__(256) void prep_kernel(
    const float* __restrict__ fc_w, const float* __restrict__ attn_l,
    const float* __restrict__ attn_r, const float* __restrict__ sem_w,
    __hip_bfloat16* __restrict__ Wf_hi, __hip_bfloat16* __restrict__ Wf_lo,
    __hip_bfloat16* __restrict__ Bs_hi, __hip_bfloat16* __restrict__ Bs_lo) {
  const int p = blockIdx.x / 33;
  const int unit = blockIdx.x % 33;
  const int t = threadIdx.x;
  if (unit < 17) {
    const float* W = fc_w + (size_t)p * 128 * 256;
    int idx = unit * 256 + t;        // < 4352 = 4*17*64
    int lane = idx & 63;
    int tmp = idx >> 6;              // kc*17 + nt
    int nt = tmp % 17, kc = tmp / 17;
    int l15 = lane & 15, quad = lane >> 4;
    __hip_bfloat16* oh = Wf_hi + (size_t)p * 34816;
    __hip_bfloat16* ol = Wf_lo + (size_t)p * 34816;
    for (int j = 0; j < 8; j++) {
      int k = kc * 32 + quad * 8 + j;
      float v;
      if (nt < 16) {
        v = W[k * 256 + nt * 16 + l15];
      } else {
        int h8 = l15 & 7;
        const float* av = ((l15 < 8) ? attn_l : attn_r) + (size_t)p * 256 + h8 * 32;
        v = 0.f;
        for (int dd = 0; dd < 32; dd++)
          v = fmaf(W[k * 256 + h8 * 32 + dd], av[dd], v);
      }
      float back, back2;
      short hb = f2bf(v, &back);
      short lb = f2bf(v - back, &back2);
      ((short*)oh)[(tmp * 64 + lane) * 8 + j] = hb;
      ((short*)ol)[(tmp * 64 + lane) * 8 + j] = lb;
    }
  } else {
    const float* Ws = sem_w + (size_t)p * 256 * 128;
    int idx = (unit - 17) * 256 + t; // < 4096 = 8*8*64
    int lane = idx & 63;
    int tmp = idx >> 6;              // kc*8 + nt
    int nt = tmp & 7, kc = tmp >> 3;
    int l15 = lane & 15, quad = lane >> 4;
    __hip_bfloat16* oh = Bs_hi + (size_t)p * 32768;
    __hip_bfloat16* ol = Bs_lo + (size_t)p * 32768;
    for (int j = 0; j < 8; j++) {
      int k = kc * 32 + quad * 8 + j;
      float v = Ws[k * 128 + nt * 16 + l15];
      float back, back2;
      short hb = f2bf(v, &back);
      short lb = f2bf(v - back, &back2);
      ((short*)oh)[(tmp * 64 + lane) * 8 + j] = hb;
      ((short*)ol)[(tmp * 64 + lane) * 8 + j] = lb;
    }
  }
}

// ---------------------------------------------------------------------------
// MFMA 1 (R10 form, reverted): all 3 paths in one dispatch, grid.y = p.
// feat = h @ W (bf16x3), in-register f32->hi/lo split, 17th N-tile = [el|er].
// ---------------------------------------------------------------------------
__global__ __launch_bounds__(64) void feat_mfma_kernel(
    const float* __restrict__ h,
    const __hip_bfloat16* __restrict__ Wf_hi_all,
    const __hip_bfloat16* __restrict__ Wf_lo_all,
    __hip_bfloat16* __restrict__ feat3, float* __restrict__ el3,
    float* __restrict__ er3) {
  const int p = blockIdx.y;
  const __hip_bfloat16* Wf_hi = Wf_hi_all + (size_t)p * 34816;
  const __hip_bfloat16* Wf_lo = Wf_lo_all + (size_t)p * 34816;
  __hip_bfloat16* feat = feat3 + (size_t)p * N_NODES * 256;
  float* el = el3 + (size_t)p * N_NODES * 8;
  float* er = er3 + (size_t)p * N_NODES * 8;

  const int lane = threadIdx.x;
  const int l15 = lane & 15, quad = lane >> 4;
  const int m0 = blockIdx.x * 16;
  const int mrow = m0 + l15;

  v4f acc[17];
#pragma unroll
  for (int nt = 0; nt < 17; nt++) acc[nt] = {0.f, 0.f, 0.f, 0.f};

#pragma unroll
  for (int kc = 0; kc < 4; kc++) {
    const float* hrow = h + (size_t)mrow * 128 + kc * 32 + quad * 8;
    float4 fa = *(const float4*)hrow;
    float4 fb = *(const float4*)(hrow + 4);
    float fv[8] = {fa.x, fa.y, fa.z, fa.w, fb.x, fb.y, fb.z, fb.w};
    short8 ahi, alo;
#pragma unroll
    for (int q = 0; q < 8; q++) {
      float back, back2;
      ahi[q] = f2bf(fv[q], &back);
      alo[q] = f2bf(fv[q] - back, &back2);
    }
#pragma unroll
    for (int nt = 0; nt < 17; nt++) {
      const int o = ((kc * 17 + nt) * 64 + lane) * 8;
      short8 bhi = *(const short8*)(Wf_hi + o);
      short8 blo = *(const short8*)(Wf_lo + o);
      acc[nt] = __builtin_amdgcn_mfma_f32_16x16x32_bf16(ahi, bhi, acc[nt], 0, 0, 0);
      acc[nt] = __builtin_amdgcn_mfma_f32_16x16x32_bf16(ahi, blo, acc[nt], 0, 0, 0);
      acc[nt] = __builtin_amdgcn_mfma_f32_16x16x32_bf16(alo, bhi, acc[nt], 0, 0, 0);
    }
  }

#pragma unroll
  for (int nt = 0; nt < 16; nt++)
#pragma unroll
    for (int r = 0; r < 4; r++) {
      int m = m0 + quad * 4 + r;
      feat[(size_t)m * 256 + nt * 16 + l15] = __float2bfloat16(acc[nt][r]);
    }
#pragma unroll
  for (int r = 0; r < 4; r++) {
    int m = m0 + quad * 4 + r;
    float v = acc[16][r];
    if (l15 < 8) el[m * 8 + l15] = v;
    else         er[m * 8 + (l15 - 8)] = v;
  }
}

// ---------------------------------------------------------------------------
// Edge helpers: SINGLE ordered stream of K independent edges for ONE node.
// All loads issued before first consume -> graduated vmcnt, max MLP.
// ---------------------------------------------------------------------------
__device__ __forceinline__ void edge8(
    const int* __restrict__ lst, int j, const float* __restrict__ el,
    float erh, const ushort* __restrict__ fp, int lane, int hh,
    float& aD, float& aN0, float& aN1, float& aN2, float& aN3) {
  int s[8];
#pragma unroll
  for (int k = 0; k < 8; k++) s[k] = lst[j + k];
  float x[8];
  ushort4 f[8];
#pragma unroll
  for (int k = 0; k < 8; k++) {
    x[k] = el[s[k] * 8 + hh];
    f[k] = *(const ushort4*)(fp + (size_t)s[k] * 256 + lane * 4);
  }
#pragma unroll
  for (int k = 0; k < 8; k++) {
    float xx = x[k] + erh;
    xx = xx > 0.f ? xx : 0.2f * xx;
    float e = __expf(xx);
    aD += e;
    aN0 = fmaf(e, bfu(f[k].x), aN0);
    aN1 = fmaf(e, bfu(f[k].y), aN1);
    aN2 = fmaf(e, bfu(f[k].z), aN2);
    aN3 = fmaf(e, bfu(f[k].w), aN3);
  }
}

__device__ __forceinline__ void edge4(
    const int* __restrict__ lst, int j, const float* __restrict__ el,
    float erh, const ushort* __restrict__ fp, int lane, int hh,
    float& aD, float& aN0, float& aN1, float& aN2, float& aN3) {
  int s[4];
#pragma unroll
  for (int k = 0; k < 4; k++) s[k] = lst[j + k];
  float x[4];
  ushort4 f[4];
#pragma unroll
  for (int k = 0; k < 4; k++) {
    x[k] = el[s[k] * 8 + hh];
    f[k] = *(const ushort4*)(fp + (size_t)s[k] * 256 + lane * 4);
  }
#pragma unroll
  for (int k = 0; k < 4; k++) {
    float xx = x[k] + erh;
    xx = xx > 0.f ? xx : 0.2f * xx;
    float e = __expf(xx);
    aD += e;
    aN0 = fmaf(e, bfu(f[k].x), aN0);
    aN1 = fmaf(e, bfu(f[k].y), aN1);
    aN2 = fmaf(e, bfu(f[k].z), aN2);
    aN3 = fmaf(e, bfu(f[k].w), aN3);
  }
}

__device__ __forceinline__ void edge1(
    const int* __restrict__ lst, int j, const float* __restrict__ el,
    float erh, const ushort* __restrict__ fp, int lane, int hh,
    float& aD, float& aN0, float& aN1, float& aN2, float& aN3) {
  int s = lst[j];
  float x = el[s * 8 + hh] + erh;
  ushort4 f0 = *(const ushort4*)(fp + (size_t)s * 256 + lane * 4);
  x = x > 0.f ? x : 0.2f * x;
  float e0 = __expf(x);
  aD += e0;
  aN0 = fmaf(e0, bfu(f0.x), aN0);
  aN1 = fmaf(e0, bfu(f0.y), aN1);
  aN2 = fmaf(e0, bfu(f0.z), aN2);
  aN3 = fmaf(e0, bfu(f0.w), aN3);
}

// ---------------------------------------------------------------------------
// Fused aggregate + semantic GEMM (R10 structure + unroll-8 edge stream).
// 512 threads (8 waves) per block; block = 16 dst nodes. Wave w aggregates
// nodes 2w, 2w+1 sequentially; lane l = channels 4l..4l+3. MFMA phase:
// wave w computes N-tile w of rows(16x256) @ sem_w(256x128) into out.
// ---------------------------------------------------------------------------
__global__ __launch_bounds__(512) void agg_sem_kernel(
    const int* __restrict__ csr_src, const int* __restrict__ off,
    const int* __restrict__ deg,
    const float* __restrict__ el, const float* __restrict__ er,
    const __hip_bfloat16* __restrict__ feat,
    const __hip_bfloat16* __restrict__ Bs_hi, const __hip_bfloat16* __restrict__ Bs_lo,
    const float* __restrict__ bias, float* __restrict__ out, int mode) {
  __shared__ float Arow[16 * LDS_STRIDE];
  const int t = threadIdx.x;
  const int w = t >> 6, lane = t & 63;
  const int hh = lane >> 3;            // head of this lane's 4 channels
  const int node_base = blockIdx.x * 16;
  const ushort* fp = (const ushort*)feat;

  // ---- edge phase: wave w aggregates nodes 2w and 2w+1 ----
#pragma unroll
  for (int i = 0; i < 2; i++) {
    const int node = node_base + 2 * w + i;
    const int n = deg[node];
    const int* lst = csr_src + off[node];
    const float erh = er[node * 8 + hh];

    float aN0 = 0.f, aN1 = 0.f, aN2 = 0.f, aN3 = 0.f, aD = 0.f;
    int j = 0;
    for (; j + 8 <= n; j += 8)
      edge8(lst, j, el, erh, fp, lane, hh, aD, aN0, aN1, aN2, aN3);
    if (j + 4 <= n) {
      edge4(lst, j, el, erh, fp, lane, hh, aD, aN0, aN1, aN2, aN3);
      j += 4;
    }
    for (; j < n; j++)
      edge1(lst, j, el, erh, fp, lane, hh, aD, aN0, aN1, aN2, aN3);

    float inv = (n > 0) ? 1.f / aD : 0.f;
    float r0 = aN0 * inv, r1 = aN1 * inv, r2 = aN2 * inv, r3 = aN3 * inv;
    r0 = r0 > 0.f ? r0 : (__expf(r0) - 1.f);
    r1 = r1 > 0.f ? r1 : (__expf(r1) - 1.f);
    r2 = r2 > 0.f ? r2 : (__expf(r2) - 1.f);
    r3 = r3 > 0.f ? r3 : (__expf(r3) - 1.f);
    *(float4*)&Arow[(2 * w + i) * LDS_STRIDE + lane * 4] =
        make_float4(r0, r1, r2, r3);
  }
  __syncthreads();

  // ---- MFMA phase: wave w -> N-tile nt = w ----
  const int nt = w;
  const int l15 = lane & 15, quad = lane >> 4;
  v4f acc = {0.f, 0.f, 0.f, 0.f};
#pragma unroll
  for (int kc = 0; kc < 8; kc++) {
    const float* ap = &Arow[l15 * LDS_STRIDE + kc * 32 + quad * 8];
    float4 a0 = *(const float4*)ap;
    float4 a1 = *(const float4*)(ap + 4);
    float fv[8] = {a0.x, a0.y, a0.z, a0.w, a1.x, a1.y, a1.z, a1.w};
    short8 ahi, alo;
#pragma unroll
    for (int q = 0; q < 8; q++) {
      float back, back2;
      ahi[q] = f2bf(fv[q], &back);
      alo[q] = f2bf(fv[q] - back, &back2);
    }
    const int o = ((kc * 8 + nt) * 64 + lane) * 8;
    short8 bhi = *(const short8*)(Bs_hi + o);
    short8 blo = *(const short8*)(Bs_lo + o);
    acc = __builtin_amdgcn_mfma_f32_16x16x32_bf16(ahi, bhi, acc, 0, 0, 0);
    acc = __builtin_amdgcn_mfma_f32_16x16x32_bf16(ahi, blo, acc, 0, 0, 0);
    acc = __builtin_amdgcn_mfma_f32_16x16x32_bf16(alo, bhi, acc, 0, 0, 0);
  }

#pragma unroll
  for (int r = 0; r < 4; r++) {
    int m = node_base + quad * 4 + r;
    size_t o = (size_t)m * 128 + nt * 16 + l15;
    float v = acc[r];
    if (mode == 0) v += bias[nt * 16 + l15];
    else           v += out[o];
    out[o] = v;
  }
}

// ---------------------------------------------------------------------------
extern "C" void kernel_launch(void* const* d_in, const int* in_sizes, int n_in,
                              void* d_out, int out_size, void* d_ws, size_t ws_size,
                              hipStream_t stream) {
  const float* h      = (const float*)d_in[0];
  const int*   ei     = (const int*)d_in[1];
  const float* fc_w   = (const float*)d_in[2];
  const float* attn_l = (const float*)d_in[3];
  const float* attn_r = (const float*)d_in[4];
  const float* sem_w  = (const float*)d_in[5];
  const float* sem_b  = (const float*)d_in[6];
  float* out = (float*)d_out;

  // workspace layout (bytes) — total ~118.4 MB (<=132.8 MB proven safe)
  char* ws = (char*)d_ws;
  __hip_bfloat16* feat3 = (__hip_bfloat16*)ws;                     // 76.8 MB
  float* el3     = (float*)(ws + 76800000);                        // 4.8 MB
  float* er3     = (float*)(ws + 81600000);                        // 4.8 MB
  int*   csr_src = (int*)(ws + 86400000);                          // 9.6 MB
  int2*  ebuf    = (int2*)(ws + 96000000);                         // 19.2 MB
  int*   deg3    = (int*)(ws + 115200000);                         // 0.6 MB
  int*   off3    = (int*)(ws + 115800000);                         // 0.6 MB
  int*   cntmat  = (int*)(ws + 116400000);                         // 602 KB
  int*   posm    = (int*)(ws + 117050000);                         // 602 KB
  int*   btot    = (int*)(ws + 117700000);                         // 2.4 KB
  int*   boff    = (int*)(ws + 117710000);                         // 2.4 KB
  __hip_bfloat16* Wf_hi = (__hip_bfloat16*)(ws + 117800000);       // 3x69632 B
  __hip_bfloat16* Wf_lo = (__hip_bfloat16*)(ws + 118050000);       // 3x69632 B
  __hip_bfloat16* Bs_hi = (__hip_bfloat16*)(ws + 118300000);       // 3x65536 B
  __hip_bfloat16* Bs_lo = (__hip_bfloat16*)(ws + 118550000);       // 3x65536 B

  // --- CSR build (deterministic counting sort) + fused weight prep ---
  blk_count_kernel<<<NCHUNKBLK, 256, 0, stream>>>(ei, cntmat);
  col_scan_kernel<<<NBKT3, 256, 0, stream>>>(cntmat, posm, btot);
  bucket_scan_kernel<<<1, 1024, 0, stream>>>(btot, boff);
  scatter_det_kernel<<<NCHUNKBLK, 256, 0, stream>>>(ei, boff, posm, ebuf);
  bucket_csr_kernel<<<NBKT3, 256, 0, stream>>>(ebuf, boff, btot, off3, deg3, csr_src);
  prep_kernel<<<NPATH * 33, 256, 0, stream>>>(fc_w, attn_l, attn_r, sem_w,
                                              Wf_hi, Wf_lo, Bs_hi, Bs_lo);

  // --- all 3 feat GEMMs in one dispatch (R10 1-tile form) ---
  feat_mfma_kernel<<<dim3(N_NODES / 16, NPATH), 64, 0, stream>>>(
      h, Wf_hi, Wf_lo, feat3, el3, er3);

  // --- fused aggregate + semantic GEMM per path (out accumulates) ---
  for (int p = 0; p < NPATH; p++) {
    agg_sem_kernel<<<N_NODES / 16, 512, 0, stream>>>(
        csr_src, off3 + p * N_NODES, deg3 + p * N_NODES,
        el3 + (size_t)p * N_NODES * 8, er3 + (size_t)p * N_NODES * 8,
        feat3 + (size_t)p * N_NODES * 256,
        Bs_hi + (size_t)p * 32768, Bs_lo + (size_t)p * 32768,
        sem_b, out, p);
  }
}